// Round 1
// baseline (231.374 us; speedup 1.0000x reference)
//
#include <hip/hip_runtime.h>
#include <math.h>

#define SEQ 8
#define FEAT 4
#define NCLASS 10

__device__ inline float2 cmul(float2 a, float2 b) {
    return make_float2(a.x * b.x - a.y * b.y, a.x * b.y + a.y * b.x);
}

// Build W = G32 ... G1 (the full per-step circuit unitary), stored TRANSPOSED:
// WT[c*256 + r] = W[r][c], so the evolve kernel's reads WT[m*256 + I] are
// lane-coalesced (lane = I).
// Column-parallel: each block owns 4 columns of W in LDS; gates mix rows
// within a column only, so blocks are independent.
__global__ __launch_bounds__(256) void build_w_kernel(
    const float* __restrict__ qrot, const float* __restrict__ qent,
    float2* __restrict__ WT) {
    __shared__ float2 col[4][256];
    const int t = threadIdx.x;
    const int cbase = blockIdx.x * 4;
#pragma unroll
    for (int ci = 0; ci < 4; ++ci)
        col[ci][t] = make_float2((t == cbase + ci) ? 1.0f : 0.0f, 0.0f);
    __syncthreads();

    for (int g = 0; g < 32; ++g) {
        const int l = g >> 4;
        const int wi = g & 15;
        int qc = -1, qt;
        const float* p;
        if (wi < 8) { qt = wi; p = qrot + (l * 8 + wi) * 3; }
        else { qc = wi - 8; qt = (qc + 1) & 7; p = qent + (l * 8 + qc) * 3; }
        const float th = p[0], ph = p[1], lam = p[2];
        const float c = cosf(0.5f * th), s = sinf(0.5f * th);
        const float2 U00 = make_float2(c, 0.0f);
        const float2 U01 = make_float2(-cosf(lam) * s, -sinf(lam) * s);
        const float2 U10 = make_float2(cosf(ph) * s, sinf(ph) * s);
        const float2 U11 = make_float2(cosf(ph + lam) * c, sinf(ph + lam) * c);
        const int bt = 7 - qt;          // wire w <-> bit (7-w)
        const int mt = 1 << bt;
        if (qc < 0) {
            // U3 on wire qt: 4 cols * 128 row-pairs = 512 disjoint updates
#pragma unroll
            for (int rep = 0; rep < 2; ++rep) {
                const int pidx = rep * 256 + t;
                const int ci = pidx >> 7;
                const int pp = pidx & 127;
                const int lo = pp & (mt - 1);
                const int r0 = ((pp ^ lo) << 1) | lo;
                const int r1 = r0 | mt;
                const float2 a = col[ci][r0];
                const float2 b = col[ci][r1];
                float2 na = cmul(U00, a), t1 = cmul(U01, b);
                na.x += t1.x; na.y += t1.y;
                float2 nb = cmul(U10, a), t2 = cmul(U11, b);
                nb.x += t2.x; nb.y += t2.y;
                col[ci][r0] = na;
                col[ci][r1] = nb;
            }
        } else {
            // CU3: rows with control bit = 1 get U3 on target bit.
            // 4 cols * 64 pairs = 256 disjoint updates.
            const int bc = 7 - qc;
            const int b1 = bc < bt ? bc : bt;
            const int b2 = bc < bt ? bt : bc;
            const int ci = t >> 6;
            int r = t & 63;
            const int lo1 = r & ((1 << b1) - 1);
            r = ((r ^ lo1) << 1) | lo1;
            const int lo2 = r & ((1 << b2) - 1);
            r = ((r ^ lo2) << 1) | lo2;
            const int r0 = r | (1 << bc);   // control=1, target=0
            const int r1 = r0 | mt;
            const float2 a = col[ci][r0];
            const float2 b = col[ci][r1];
            float2 na = cmul(U00, a), t1 = cmul(U01, b);
            na.x += t1.x; na.y += t1.y;
            float2 nb = cmul(U10, a), t2 = cmul(U11, b);
            nb.x += t2.x; nb.y += t2.y;
            col[ci][r0] = na;
            col[ci][r1] = nb;
        }
        __syncthreads();
    }
#pragma unroll
    for (int ci = 0; ci < 4; ++ci)
        WT[(cbase + ci) * 256 + t] = col[ci][t];
}

// One block per batch element; 8 sequential steps.
// Carried state: red (16x16 complex) = partial trace of dephased rho.
// Per step (rank-1 encoding w, real):
//   Wv[I,j]  = sum_k W[I,(j,k)] * w[k]              (registers + LDS copy)
//   G[I,j']  = sum_j Wv[I,j] * red[j,j']            (registers)
//   P[f,m,m']= sum_j' G[(f,m),j'] * conj(Wv[(f,m'),j'])
//   diag[(f,m)] = Re P[f,m,m]  -> 8 Z-expectations via wave reductions
//   red'[m,m'] = exp(-g^2/2 * popc(m^m')) * sum_f P[f,m,m']
__global__ __launch_bounds__(256) void evolve_kernel(
    const float* __restrict__ x, const float* __restrict__ g_raw_p,
    const float* __restrict__ fc_w, const float* __restrict__ fc_b,
    const float2* __restrict__ WT, float* __restrict__ out) {
    __shared__ float2 redS[16][16];
    __shared__ float2 WvS[256][17];     // padded: avoid 64-way bank conflicts
    __shared__ float2 bufS[4][16][16];  // per-wave partial f-sums of P
    __shared__ float w16s[16];
    __shared__ float partS[4][8];
    __shared__ float featsS[64];

    const int tid = threadIdx.x;
    const int b = blockIdx.x;
    const int f = tid >> 4;
    const int m = tid & 15;

    redS[f][m] = make_float2(tid == 0 ? 1.0f : 0.0f, 0.0f);
    const float g = log1pf(expf(g_raw_p[0]));   // softplus
    const float negg2 = -0.5f * g * g;
    __syncthreads();

    for (int t = 0; t < SEQ; ++t) {
        // ---- encoding amplitudes: w[k] = prod_i amp_i((k>>i)&1), real
        if (tid < 16) {
            float prod = 1.0f;
#pragma unroll
            for (int i = 0; i < FEAT; ++i) {
                const float xv = x[(b * SEQ + t) * FEAT + i];
                prod *= ((tid >> i) & 1) ? sqrtf(xv) : sqrtf(1.0f - xv);
            }
            w16s[tid] = prod;
        }
        __syncthreads();
        float w16[16];
#pragma unroll
        for (int k = 0; k < 16; ++k) w16[k] = w16s[k];

        // ---- Wv[tid][j] (complex * real), coalesced reads of WT
        float2 Wv[16];
        const float2* wrow = WT + tid;
#pragma unroll
        for (int j = 0; j < 16; ++j) {
            float2 acc = make_float2(0.0f, 0.0f);
#pragma unroll
            for (int k = 0; k < 16; ++k) {
                const float2 wv = wrow[(j * 16 + k) * 256];
                acc.x = fmaf(wv.x, w16[k], acc.x);
                acc.y = fmaf(wv.y, w16[k], acc.y);
            }
            Wv[j] = acc;
            WvS[tid][j] = acc;
        }

        // ---- G[j'] = sum_j Wv[j] * red[j][j']   (red broadcast from LDS)
        float2 G[16];
#pragma unroll
        for (int jp = 0; jp < 16; ++jp) G[jp] = make_float2(0.0f, 0.0f);
#pragma unroll
        for (int j = 0; j < 16; ++j) {
            const float2 a = Wv[j];
#pragma unroll
            for (int jp = 0; jp < 16; ++jp) {
                const float2 r = redS[j][jp];
                G[jp].x += a.x * r.x - a.y * r.y;
                G[jp].y += a.x * r.y + a.y * r.x;
            }
        }
        __syncthreads();   // WvS visible to all; red reads complete

        // ---- P[mp] = sum_j' G[j'] * conj(WvS[f*16+mp][j'])
        float2 P[16];
#pragma unroll
        for (int mp = 0; mp < 16; ++mp) {
            float2 acc = make_float2(0.0f, 0.0f);
#pragma unroll
            for (int jp = 0; jp < 16; ++jp) {
                const float2 gg = G[jp];
                const float2 wv = WvS[f * 16 + mp][jp];
                acc.x += gg.x * wv.x + gg.y * wv.y;
                acc.y += gg.y * wv.x - gg.x * wv.y;
            }
            P[mp] = acc;
        }
        const float dval = P[m].x;   // diag[(f,m)] before f-reduction

        // ---- 8 Z-expectations: signed wave reductions of dval
#pragma unroll
        for (int w = 0; w < 8; ++w) {
            float v = ((tid >> (7 - w)) & 1) ? -dval : dval;
#pragma unroll
            for (int off = 32; off >= 1; off >>= 1)
                v += __shfl_xor(v, off, 64);
            if ((tid & 63) == 0) partS[tid >> 6][w] = v;
        }

        // ---- reduce P over f (lane bits 4-5 within wave, then LDS across waves)
#pragma unroll
        for (int mp = 0; mp < 16; ++mp) {
            float2 v = P[mp];
            v.x += __shfl_xor(v.x, 16, 64);
            v.y += __shfl_xor(v.y, 16, 64);
            v.x += __shfl_xor(v.x, 32, 64);
            v.y += __shfl_xor(v.y, 32, 64);
            P[mp] = v;
        }
        if (((tid >> 4) & 3) == 0) {      // one lane-group per wave writes
#pragma unroll
            for (int mp = 0; mp < 16; ++mp) bufS[tid >> 6][m][mp] = P[mp];
        }
        __syncthreads();   // bufS + partS visible; WvS reads complete

        if (tid < 8)
            featsS[t * 8 + tid] =
                partS[0][tid] + partS[1][tid] + partS[2][tid] + partS[3][tid];

        // red'[m2][mp2]; thread tid = m2*16 + mp2  (reuse f,m decode)
        float2 rsum = make_float2(0.0f, 0.0f);
#pragma unroll
        for (int w = 0; w < 4; ++w) {
            const float2 p = bufS[w][f][m];
            rsum.x += p.x; rsum.y += p.y;
        }
        const float dp = expf(negg2 * (float)__popc(f ^ m));
        redS[f][m] = make_float2(rsum.x * dp, rsum.y * dp);
        __syncthreads();   // red visible; bufS free for next step
    }

    // ---- FC epilogue: out[b,c] = feats . fc_w[c,:] + fc_b[c]
    if (tid < NCLASS) {
        float acc = fc_b[tid];
#pragma unroll
        for (int q = 0; q < 64; ++q)
            acc = fmaf(featsS[q], fc_w[tid * 64 + q], acc);
        out[b * NCLASS + tid] = acc;
    }
}

extern "C" void kernel_launch(void* const* d_in, const int* in_sizes, int n_in,
                              void* d_out, int out_size, void* d_ws, size_t ws_size,
                              hipStream_t stream) {
    (void)in_sizes; (void)n_in; (void)out_size; (void)ws_size;
    const float* x    = (const float*)d_in[0];
    const float* qrot = (const float*)d_in[1];
    const float* qent = (const float*)d_in[2];
    const float* graw = (const float*)d_in[3];
    const float* fcw  = (const float*)d_in[4];
    const float* fcb  = (const float*)d_in[5];
    float* out = (float*)d_out;
    float2* WT = (float2*)d_ws;   // 256*256 complex = 512 KB

    build_w_kernel<<<64, 256, 0, stream>>>(qrot, qent, WT);
    evolve_kernel<<<64, 256, 0, stream>>>(x, graw, fcw, fcb, WT, out);
}

// Round 3
// 138.279 us; speedup vs baseline: 1.6732x; 1.6732x over previous
//
#include <hip/hip_runtime.h>
#include <math.h>

#define SEQ 8
#define NCLASS 10

__device__ inline float2 cmul(float2 a, float2 b) {
    return make_float2(a.x * b.x - a.y * b.y, a.x * b.y + a.y * b.x);
}

// ---------------------------------------------------------------------------
// build_w: W = G32...G1 stored transposed WT[c*256 + r] = W[r][c].
// One WAVE per column, column in registers (4 complex/lane: lane L holds rows
// 4L..4L+3). Row-pair exchange via __shfl_xor; zero __syncthreads.
// ---------------------------------------------------------------------------
__global__ __launch_bounds__(256) void build_w_kernel(
    const float* __restrict__ qrot, const float* __restrict__ qent,
    float2* __restrict__ WT) {
    const int lane = threadIdx.x & 63;
    const int col = blockIdx.x * 4 + (threadIdx.x >> 6);
    const int rbase = lane * 4;
    float2 a[4];
#pragma unroll
    for (int i = 0; i < 4; ++i)
        a[i] = make_float2((rbase + i) == col ? 1.0f : 0.0f, 0.0f);

    for (int g = 0; g < 32; ++g) {
        const int l = g >> 4, wi = g & 15;
        int bc = -1, qt;
        const float* p;
        if (wi < 8) { qt = wi; p = qrot + (l * 8 + wi) * 3; }
        else { const int qc = wi - 8; qt = (qc + 1) & 7; p = qent + (l * 8 + qc) * 3; bc = 7 - qc; }
        const float th = p[0], ph = p[1], lam = p[2];
        const float c = cosf(0.5f * th), s = sinf(0.5f * th);
        const float2 U00 = make_float2(c, 0.0f);
        const float2 U01 = make_float2(-cosf(lam) * s, -sinf(lam) * s);
        const float2 U10 = make_float2(cosf(ph) * s, sinf(ph) * s);
        const float2 U11 = make_float2(cosf(ph + lam) * c, sinf(ph + lam) * c);
        const int bt = 7 - qt, mt = 1 << bt;
        if (bt >= 2) {
            const int pl = mt >> 2;                  // partner lane xor mask
            const int side = (lane >> (bt - 2)) & 1; // row's target-bit value
            float2 br[4];
#pragma unroll
            for (int i = 0; i < 4; ++i) {
                br[i].x = __shfl_xor(a[i].x, pl, 64);
                br[i].y = __shfl_xor(a[i].y, pl, 64);
            }
#pragma unroll
            for (int i = 0; i < 4; ++i) {
                const int r = rbase + i;
                float2 na, tt;
                if (side) { na = cmul(U10, br[i]); tt = cmul(U11, a[i]); }
                else      { na = cmul(U00, a[i]); tt = cmul(U01, br[i]); }
                na.x += tt.x; na.y += tt.y;
                const bool act = (bc < 0) || ((r >> bc) & 1);
                if (act) a[i] = na;
            }
        } else {
#pragma unroll
            for (int i0 = 0; i0 < 4; ++i0) {
                if (i0 & mt) continue;
                const int i1 = i0 | mt;
                const int r0 = rbase + i0;
                const bool act = (bc < 0) || ((r0 >> bc) & 1);
                const float2 a0 = a[i0], a1 = a[i1];
                float2 n0 = cmul(U00, a0), t1 = cmul(U01, a1);
                n0.x += t1.x; n0.y += t1.y;
                float2 n1 = cmul(U10, a0), t2 = cmul(U11, a1);
                n1.x += t2.x; n1.y += t2.y;
                if (act) { a[i0] = n0; a[i1] = n1; }
            }
        }
    }
    float4* dst = (float4*)&WT[col * 256 + rbase];
    dst[0] = make_float4(a[0].x, a[0].y, a[1].x, a[1].y);
    dst[1] = make_float4(a[2].x, a[2].y, a[3].x, a[3].y);
}

// ---------------------------------------------------------------------------
// wv: Wv[t][b][j][I] = sum_k W[I][(j,k)] * w16[b,t,k]   (red-independent ->
// hoisted out of the sequential loop; 512 independent blocks).
// ---------------------------------------------------------------------------
__global__ __launch_bounds__(256) void wv_kernel(
    const float* __restrict__ x, const float2* __restrict__ WT,
    float2* __restrict__ Wv) {
    __shared__ float w16s[16];
    const int tid = threadIdx.x;
    const int b = blockIdx.x & 63;
    const int t = blockIdx.x >> 6;
    if (tid < 16) {
        float prod = 1.0f;
#pragma unroll
        for (int i = 0; i < 4; ++i) {
            const float xv = x[(b * SEQ + t) * 4 + i];
            prod *= ((tid >> i) & 1) ? sqrtf(xv) : sqrtf(1.0f - xv);
        }
        w16s[tid] = prod;
    }
    __syncthreads();
    float w16[16];
#pragma unroll
    for (int k = 0; k < 16; ++k) w16[k] = w16s[k];
    const float2* wrow = WT + tid;
    float2* ov = Wv + (t * 64 + b) * 4096 + tid;
#pragma unroll
    for (int j = 0; j < 16; ++j) {
        float2 acc = make_float2(0.0f, 0.0f);
#pragma unroll
        for (int k = 0; k < 16; ++k) {
            const float2 wv = wrow[(j * 16 + k) * 256];
            acc.x = fmaf(wv.x, w16[k], acc.x);
            acc.y = fmaf(wv.y, w16[k], acc.y);
        }
        ov[j * 256] = acc;
    }
}

// ---------------------------------------------------------------------------
// evolve: 64 blocks x 1024 threads (16 waves, 4/SIMD). Per step:
//   H[I][jp]      = sum_j Wv[I][j] red[j][jp]        thread (q,I): jp=4q..4q+3
//   SS[q][m][mp]  = sum_{f=4q..4q+3} sum_jp H[(f,m)][jp] conj(Wv[(f,mp)][jp])
//   diag[(f,m)] falls out free at mp==m; red' = deph .* sum_q SS[q].
// FIX vs R2: f spans 16 values -> each P-thread loops 4 f's (R2 only did f=q).
// ---------------------------------------------------------------------------
__global__ __launch_bounds__(1024, 4) void evolve_kernel(
    const float* __restrict__ g_raw_p,
    const float* __restrict__ fc_w, const float* __restrict__ fc_b,
    const float2* __restrict__ Wv, float* __restrict__ out) {
    __shared__ float2 WvS[16][256];
    __shared__ float2 HS[16][256];
    __shared__ float2 SS[4][16][16];
    __shared__ float DdS[256];
    __shared__ float2 redS[16][16];
    __shared__ float partS[4][8];
    __shared__ float featsS[64];

    const int tid = threadIdx.x;
    const int b = blockIdx.x;
    const int q = tid >> 8;        // 0..3: jp-group in H phase, f-group in P
    const int I = tid & 255;
    const int m = (tid >> 4) & 15;
    const int mp = tid & 15;

    if (tid < 256) redS[tid >> 4][tid & 15] = make_float2(tid == 0 ? 1.0f : 0.0f, 0.0f);
    const float g = log1pf(expf(g_raw_p[0]));   // softplus
    const float negg2 = -0.5f * g * g;

    // prologue: stage Wv tile for t=0
    {
        const float2* src = Wv + (0 * 64 + b) * 4096;
#pragma unroll
        for (int jj = 0; jj < 4; ++jj)
            WvS[q * 4 + jj][I] = src[(q * 4 + jj) * 256 + I];
    }
    __syncthreads();

    for (int t = 0; t < SEQ; ++t) {
        // ---- H[I][jp], jp = q*4..q*4+3
        float2 hacc[4];
#pragma unroll
        for (int jj = 0; jj < 4; ++jj) hacc[jj] = make_float2(0.0f, 0.0f);
#pragma unroll
        for (int j = 0; j < 16; ++j) {
            const float2 wv = WvS[j][I];
#pragma unroll
            for (int jj = 0; jj < 4; ++jj) {
                const float2 r = redS[j][q * 4 + jj];
                hacc[jj].x += wv.x * r.x - wv.y * r.y;
                hacc[jj].y += wv.x * r.y + wv.y * r.x;
            }
        }
#pragma unroll
        for (int jj = 0; jj < 4; ++jj) HS[q * 4 + jj][I] = hacc[jj];
        __syncthreads();

        // ---- P phase: f = 4q..4q+3; SS[q] = partial f-sum
        float2 acc = make_float2(0.0f, 0.0f);
#pragma unroll
        for (int ff = 0; ff < 4; ++ff) {
            const int fI = (q * 4 + ff) << 4;
            const int Im = fI | m;
            const int Ip = fI | mp;
            float2 a2 = make_float2(0.0f, 0.0f);
#pragma unroll
            for (int jp = 0; jp < 16; ++jp) {
                const float2 h = HS[jp][Im];
                const float2 wv = WvS[jp][Ip];
                a2.x += h.x * wv.x + h.y * wv.y;   // h * conj(wv)
                a2.y += h.y * wv.x - h.x * wv.y;
            }
            acc.x += a2.x; acc.y += a2.y;
            if (mp == m) DdS[Im] = a2.x;
        }
        SS[q][m][mp] = acc;
        __syncthreads();

        // ---- tail (waves 0-3) + stage next Wv tile (all waves)
        if (tid < 256) {
            float2 rsum = make_float2(0.0f, 0.0f);
#pragma unroll
            for (int ff = 0; ff < 4; ++ff) {
                const float2 v = SS[ff][m][mp];
                rsum.x += v.x; rsum.y += v.y;
            }
            const float dpv = expf(negg2 * (float)__popc(m ^ mp));
            redS[m][mp] = make_float2(rsum.x * dpv, rsum.y * dpv);

            const float dval = DdS[tid];
#pragma unroll
            for (int w = 0; w < 8; ++w) {
                float v = ((tid >> (7 - w)) & 1) ? -dval : dval;
#pragma unroll
                for (int off = 32; off >= 1; off >>= 1)
                    v += __shfl_xor(v, off, 64);
                if ((tid & 63) == 0) partS[tid >> 6][w] = v;
            }
        }
        if (t + 1 < SEQ) {   // WvS free after the P barrier; overlap with tail
            const float2* src = Wv + ((t + 1) * 64 + b) * 4096;
#pragma unroll
            for (int jj = 0; jj < 4; ++jj)
                WvS[q * 4 + jj][I] = src[(q * 4 + jj) * 256 + I];
        }
        __syncthreads();
        if (tid < 8)
            featsS[t * 8 + tid] =
                partS[0][tid] + partS[1][tid] + partS[2][tid] + partS[3][tid];
        // next iteration's first barrier (after H) orders featsS/partS reuse;
        // redS reads in H are ordered by the barrier just above.
    }
    __syncthreads();

    if (tid < NCLASS) {
        float acc = fc_b[tid];
#pragma unroll
        for (int qq = 0; qq < 64; ++qq)
            acc = fmaf(featsS[qq], fc_w[tid * 64 + qq], acc);
        out[b * NCLASS + tid] = acc;
    }
}

extern "C" void kernel_launch(void* const* d_in, const int* in_sizes, int n_in,
                              void* d_out, int out_size, void* d_ws, size_t ws_size,
                              hipStream_t stream) {
    (void)in_sizes; (void)n_in; (void)out_size; (void)ws_size;
    const float* x    = (const float*)d_in[0];
    const float* qrot = (const float*)d_in[1];
    const float* qent = (const float*)d_in[2];
    const float* graw = (const float*)d_in[3];
    const float* fcw  = (const float*)d_in[4];
    const float* fcb  = (const float*)d_in[5];
    float* out = (float*)d_out;

    float2* WT = (float2*)d_ws;                         // 512 KB
    float2* Wv = (float2*)((char*)d_ws + 524288);       // 16 MB: [8][64][16*256]

    build_w_kernel<<<64, 256, 0, stream>>>(qrot, qent, WT);
    wv_kernel<<<512, 256, 0, stream>>>(x, WT, Wv);
    evolve_kernel<<<64, 1024, 0, stream>>>(graw, fcw, fcb, Wv, out);
}